// Round 3
// baseline (224.907 us; speedup 1.0000x reference)
//
#include <hip/hip_runtime.h>
#include <hip/hip_bf16.h>

typedef short bf16x8 __attribute__((ext_vector_type(8)));
typedef float f32x4 __attribute__((ext_vector_type(4)));

#define NB 8
#define SS 2048
#define DD 1024
#define RR 128

__device__ __forceinline__ short f2bf(float x){
  unsigned u = __float_as_uint(x);
  u += 0x7fffu + ((u >> 16) & 1u);
  return (short)(u >> 16);
}
__device__ __forceinline__ float bf2f(short h){
  return __uint_as_float(((unsigned)(unsigned short)h) << 16);
}
__device__ __forceinline__ void gload16(const void* g, void* l){
  __builtin_amdgcn_global_load_lds((const __attribute__((address_space(1))) unsigned*)g,
                                   (__attribute__((address_space(3))) unsigned*)l, 16, 0, 0);
}
// swizzled short-index into a [rows][64] bf16 tile: 16B-slot col XORed with row&7 (T2 involution)
__device__ __forceinline__ int swz(int row, int c16){
  return row * 64 + ((c16 ^ (row & 7)) << 3);
}

// -------- Kernel 0: transpose proj (D x R) -> pt (R x D), split into bf16 hi/lo
__global__ __launch_bounds__(256) void k0_proj(const float* __restrict__ proj,
                                               short* __restrict__ pt_hi,
                                               short* __restrict__ pt_lo){
  __shared__ float tile[64][65];
  const int d0 = blockIdx.x * 64, r0 = blockIdx.y * 64;
  const int tid = threadIdx.x;
  #pragma unroll
  for (int i = 0; i < 16; ++i){
    int u = i * 256 + tid;
    int d = u >> 6, r = u & 63;
    tile[d][r] = proj[(d0 + d) * RR + r0 + r];
  }
  __syncthreads();
  #pragma unroll
  for (int i = 0; i < 16; ++i){
    int u = i * 256 + tid;
    int r = u >> 6, d = u & 63;
    float x = tile[d][r];
    short h = f2bf(x);
    short l = f2bf(x - bf2f(h));
    pt_hi[(r0 + r) * DD + d0 + d] = h;
    pt_lo[(r0 + r) * DD + d0 + d] = l;
  }
}

// -------- Kernel 1: t = batch @ proj via split-bf16 MFMA (hh + hl + lh; ll dropped, ~2^-17 rel).
// 512 thr (8 waves: wr=w&3 row-16-group, wc=w>>2 col-64-group), 64 rows/block, grid 256 (1 block/CU).
__global__ __launch_bounds__(512, 2) void k1_gemm1(const float* __restrict__ batch,
                                                   const short* __restrict__ pt_hi,
                                                   const short* __restrict__ pt_lo,
                                                   short* __restrict__ t_hi,
                                                   short* __restrict__ t_lo,
                                                   float* __restrict__ sqv){
  __shared__ short Ah[64 * 64], Al[64 * 64];       // 8 KB each, swizzled
  __shared__ short Ph[128 * 64], Pl[128 * 64];     // 16 KB each, swizzled
  __shared__ float sqpart[64];
  const int tid = threadIdx.x;
  const int w = tid >> 6, lane = tid & 63;
  const int lr = lane & 15, lg = lane >> 4;
  const int wr = w & 3, wc = w >> 2;
  const int row0 = blockIdx.x * 64;
  const int colg = (lane & 7) ^ (lane >> 3);       // pre-swizzled global 16B-col for gload16
  if (tid < 64) sqpart[tid] = 0.f;
  f32x4 acc[4] = {{0.f,0.f,0.f,0.f}};
  #pragma unroll 1
  for (int k0 = 0; k0 < DD; k0 += 64){
    // stage A tile (64 rows x 64 k): fp32 -> hi/lo bf16, swizzled reg-staging
    #pragma unroll
    for (int i = 0; i < 2; ++i){
      int u = tid * 2 + i;
      int r = u >> 4, kc = (u & 15) * 4;
      float4 v = *(const float4*)(batch + (size_t)(row0 + r) * DD + k0 + kc);
      short4 hv, lv;
      hv.x = f2bf(v.x); lv.x = f2bf(v.x - bf2f(hv.x));
      hv.y = f2bf(v.y); lv.y = f2bf(v.y - bf2f(hv.y));
      hv.z = f2bf(v.z); lv.z = f2bf(v.z - bf2f(hv.z));
      hv.w = f2bf(v.w); lv.w = f2bf(v.w - bf2f(hv.w));
      int sidx = r * 64 + (((kc >> 3) ^ (r & 7)) << 3) + (kc & 7);
      *(short4*)&Ah[sidx] = hv;
      *(short4*)&Al[sidx] = lv;
    }
    // stage P tile (128 cols x 64 k) via global_load_lds: linear LDS dest + pre-swizzled source
    #pragma unroll
    for (int q = 0; q < 2; ++q){
      int prow = w * 16 + q * 8 + (lane >> 3);
      const short* gh = pt_hi + prow * DD + k0 + colg * 8;
      const short* gl = pt_lo + prow * DD + k0 + colg * 8;
      gload16(gh, &Ph[w * 1024 + q * 512]);
      gload16(gl, &Pl[w * 1024 + q * 512]);
    }
    __syncthreads();
    #pragma unroll
    for (int ks = 0; ks < 2; ++ks){
      int c16 = ks * 4 + lg;
      bf16x8 ah = *(const bf16x8*)&Ah[swz(wr * 16 + lr, c16)];
      bf16x8 al = *(const bf16x8*)&Al[swz(wr * 16 + lr, c16)];
      bf16x8 bh[4], bl[4];
      #pragma unroll
      for (int n = 0; n < 4; ++n){
        int prow = wc * 64 + n * 16 + lr;
        bh[n] = *(const bf16x8*)&Ph[swz(prow, c16)];
        bl[n] = *(const bf16x8*)&Pl[swz(prow, c16)];
      }
      #pragma unroll
      for (int n = 0; n < 4; ++n)
        acc[n] = __builtin_amdgcn_mfma_f32_16x16x32_bf16(ah, bh[n], acc[n], 0, 0, 0);
      #pragma unroll
      for (int n = 0; n < 4; ++n)
        acc[n] = __builtin_amdgcn_mfma_f32_16x16x32_bf16(ah, bl[n], acc[n], 0, 0, 0);
      #pragma unroll
      for (int n = 0; n < 4; ++n)
        acc[n] = __builtin_amdgcn_mfma_f32_16x16x32_bf16(al, bh[n], acc[n], 0, 0, 0);
    }
    __syncthreads();
  }
  // epilogue: split t into hi/lo bf16, accumulate row norms across the two col-split waves
  #pragma unroll
  for (int r = 0; r < 4; ++r){
    int lrow = wr * 16 + lg * 4 + r;
    int grow = row0 + lrow;
    float s = 0.f;
    #pragma unroll
    for (int n = 0; n < 4; ++n){
      float x = acc[n][r];
      s += x * x;
      int col = wc * 64 + n * 16 + lr;
      short h = f2bf(x);
      short l = f2bf(x - bf2f(h));
      t_hi[(size_t)grow * RR + col] = h;
      t_lo[(size_t)grow * RR + col] = l;
    }
    s += __shfl_xor(s, 1);
    s += __shfl_xor(s, 2);
    s += __shfl_xor(s, 4);
    s += __shfl_xor(s, 8);
    if (lr == 0) atomicAdd(&sqpart[lrow], s);
  }
  __syncthreads();
  if (tid < 64) sqv[row0 + tid] = sqpart[tid];
}

// -------- Kernel 2: symmetric pairwise distances. Tile-pairs ti<=tj; mirror written from regs.
// Static LDS exactly 64 KB (sq values read straight from global in the epilogue — L2-hit).
__global__ __launch_bounds__(256, 2) void k2_dist(const short* __restrict__ t_hi,
                                                  const short* __restrict__ t_lo,
                                                  const float* __restrict__ sqv,
                                                  float* __restrict__ out){
  __shared__ short Ah[128 * 64], Al[128 * 64];   // 16 KB each, swizzled
  __shared__ short Bh[128 * 64], Bl[128 * 64];
  const int tid = threadIdx.x;
  const int w = tid >> 6, lane = tid & 63;
  const int lr = lane & 15, lg = lane >> 4;
  const int bi = blockIdx.z;
  // decode tile pair (ti <= tj) from blockIdx.x in [0,136)
  int p = blockIdx.x;
  int ti = 0;
  while (p >= 16 - ti){ p -= 16 - ti; ++ti; }
  const int tj = ti + p;
  const int i0 = ti * 128, j0 = tj * 128;
  const size_t tbase = (size_t)bi * SS * RR;
  const int colg = (lane & 7) ^ (lane >> 3);

  f32x4 acc[16] = {{0.f,0.f,0.f,0.f}};
  #pragma unroll 1
  for (int k0 = 0; k0 < RR; k0 += 64){
    // stage 4 panels (128 x 64 bf16 each) via global_load_lds, pre-swizzled source
    #pragma unroll
    for (int q = 0; q < 4; ++q){
      int rloc = w * 32 + q * 8 + (lane >> 3);
      size_t goffA = tbase + (size_t)(i0 + rloc) * RR + k0 + colg * 8;
      size_t goffB = tbase + (size_t)(j0 + rloc) * RR + k0 + colg * 8;
      int ldst = w * 2048 + q * 512;
      gload16(t_hi + goffA, &Ah[ldst]);
      gload16(t_lo + goffA, &Al[ldst]);
      gload16(t_hi + goffB, &Bh[ldst]);
      gload16(t_lo + goffB, &Bl[ldst]);
    }
    __syncthreads();
    #pragma unroll
    for (int ks = 0; ks < 2; ++ks){
      int c16 = ks * 4 + lg;
      bf16x8 ah[2], al[2];
      #pragma unroll
      for (int rt = 0; rt < 2; ++rt){
        int arow = w * 32 + rt * 16 + lr;
        ah[rt] = *(const bf16x8*)&Ah[swz(arow, c16)];
        al[rt] = *(const bf16x8*)&Al[swz(arow, c16)];
      }
      bf16x8 bh[8], bl[8];
      #pragma unroll
      for (int n = 0; n < 8; ++n){
        int brow = n * 16 + lr;
        bh[n] = *(const bf16x8*)&Bh[swz(brow, c16)];
        bl[n] = *(const bf16x8*)&Bl[swz(brow, c16)];
      }
      #pragma unroll
      for (int rt = 0; rt < 2; ++rt)
        #pragma unroll
        for (int n = 0; n < 8; ++n)
          acc[rt * 8 + n] = __builtin_amdgcn_mfma_f32_16x16x32_bf16(ah[rt], bh[n], acc[rt * 8 + n], 0, 0, 0);
      #pragma unroll
      for (int rt = 0; rt < 2; ++rt)
        #pragma unroll
        for (int n = 0; n < 8; ++n)
          acc[rt * 8 + n] = __builtin_amdgcn_mfma_f32_16x16x32_bf16(ah[rt], bl[n], acc[rt * 8 + n], 0, 0, 0);
      #pragma unroll
      for (int rt = 0; rt < 2; ++rt)
        #pragma unroll
        for (int n = 0; n < 8; ++n)
          acc[rt * 8 + n] = __builtin_amdgcn_mfma_f32_16x16x32_bf16(al[rt], bh[n], acc[rt * 8 + n], 0, 0, 0);
    }
    __syncthreads();
  }
  // epilogue: d2 = sq_i + sq_j - 2*dots; direct tile scalar stores, mirror tile float4 from regs
  float* outb = out + (size_t)bi * SS * SS;
  const float* sqb = sqv + bi * SS;
  float sqj_reg[8];
  #pragma unroll
  for (int n = 0; n < 8; ++n) sqj_reg[n] = sqb[j0 + n * 16 + lr];
  #pragma unroll
  for (int rt = 0; rt < 2; ++rt){
    int rbase = w * 32 + rt * 16 + lg * 4;
    float sqi_reg[4];
    #pragma unroll
    for (int r = 0; r < 4; ++r) sqi_reg[r] = sqb[i0 + rbase + r];
    #pragma unroll
    for (int n = 0; n < 8; ++n){
      int col = n * 16 + lr;
      float4 mv;
      #pragma unroll
      for (int r = 0; r < 4; ++r){
        int row = rbase + r;
        float v = sqi_reg[r] + sqj_reg[n] - 2.0f * acc[rt * 8 + n][r];
        outb[(size_t)(i0 + row) * SS + (j0 + col)] = v;
        ((float*)&mv)[r] = v;
      }
      if (ti != tj)
        *(float4*)&outb[(size_t)(j0 + col) * SS + (i0 + rbase)] = mv;
    }
  }
}

extern "C" void kernel_launch(void* const* d_in, const int* in_sizes, int n_in,
                              void* d_out, int out_size, void* d_ws, size_t ws_size,
                              hipStream_t stream) {
  const float* batch = (const float*)d_in[0];   // (8, 2048, 1024) f32
  const float* proj  = (const float*)d_in[1];   // (1024, 128) f32
  float* out = (float*)d_out;                   // (8, 2048, 2048) f32
  char* ws = (char*)d_ws;

  short* pt_hi = (short*)(ws);                          // 128x1024 bf16 = 256 KB
  short* pt_lo = (short*)(ws + 262144);                 // 256 KB
  short* t_hi  = (short*)(ws + 524288);                 // 16384x128 bf16 = 4 MB
  short* t_lo  = (short*)(ws + 4718592);                // 4 MB
  float* sqv   = (float*)(ws + 8912896);                // 16384 f32 = 64 KB

  k0_proj<<<dim3(16, 2), 256, 0, stream>>>(proj, pt_hi, pt_lo);
  k1_gemm1<<<dim3(256), 512, 0, stream>>>(batch, pt_hi, pt_lo, t_hi, t_lo, sqv);
  k2_dist<<<dim3(136, 1, 8), 256, 0, stream>>>(t_hi, t_lo, sqv, out);
}

// Round 4
// 215.269 us; speedup vs baseline: 1.0448x; 1.0448x over previous
//
#include <hip/hip_runtime.h>
#include <hip/hip_bf16.h>

typedef short bf16x8 __attribute__((ext_vector_type(8)));
typedef float f32x4 __attribute__((ext_vector_type(4)));

#define NB 8
#define SS 2048
#define DD 1024
#define RR 128

__device__ __forceinline__ short f2bf(float x){
  unsigned u = __float_as_uint(x);
  u += 0x7fffu + ((u >> 16) & 1u);
  return (short)(u >> 16);
}
__device__ __forceinline__ float bf2f(short h){
  return __uint_as_float(((unsigned)(unsigned short)h) << 16);
}
__device__ __forceinline__ void gload16(const void* g, void* l){
  __builtin_amdgcn_global_load_lds((const __attribute__((address_space(1))) unsigned*)g,
                                   (__attribute__((address_space(3))) unsigned*)l, 16, 0, 0);
}
// swizzled short-index into a [rows][64] bf16 tile: 16B-slot col XORed with row&7 (T2 involution)
__device__ __forceinline__ int swz(int row, int c16){
  return row * 64 + ((c16 ^ (row & 7)) << 3);
}

// -------- Kernel 0: transpose proj (D x R) -> pt (R x D), split into bf16 hi/lo
__global__ __launch_bounds__(256) void k0_proj(const float* __restrict__ proj,
                                               short* __restrict__ pt_hi,
                                               short* __restrict__ pt_lo){
  __shared__ float tile[64][65];
  const int d0 = blockIdx.x * 64, r0 = blockIdx.y * 64;
  const int tid = threadIdx.x;
  #pragma unroll
  for (int i = 0; i < 16; ++i){
    int u = i * 256 + tid;
    int d = u >> 6, r = u & 63;
    tile[d][r] = proj[(d0 + d) * RR + r0 + r];
  }
  __syncthreads();
  #pragma unroll
  for (int i = 0; i < 16; ++i){
    int u = i * 256 + tid;
    int r = u >> 6, d = u & 63;
    float x = tile[d][r];
    short h = f2bf(x);
    short l = f2bf(x - bf2f(h));
    pt_hi[(r0 + r) * DD + d0 + d] = h;
    pt_lo[(r0 + r) * DD + d0 + d] = l;
  }
}

// -------- Kernel 1: t = batch @ proj via split-bf16 MFMA (hh + hl + lh; ll dropped).
// 512 thr (8 waves: wr=w&3 row-16-group, wc=w>>2 col-64-group), 64 rows/block, grid 256.
// Epilogue bounces t through the dead P panels for coalesced int4 stores.
__global__ __launch_bounds__(512, 2) void k1_gemm1(const float* __restrict__ batch,
                                                   const short* __restrict__ pt_hi,
                                                   const short* __restrict__ pt_lo,
                                                   short* __restrict__ t_hi,
                                                   short* __restrict__ t_lo,
                                                   float* __restrict__ sqv){
  __shared__ __align__(16) char smem[49408];   // Ah 8K | Al 8K | Ph 16K | Pl 16K | sqpart 256B
  short* Ah = (short*)smem;
  short* Al = (short*)(smem + 8192);
  short* Ph = (short*)(smem + 16384);
  short* Pl = (short*)(smem + 32768);
  float* sqpart = (float*)(smem + 49152);
  const int tid = threadIdx.x;
  const int w = tid >> 6, lane = tid & 63;
  const int lr = lane & 15, lg = lane >> 4;
  const int wr = w & 3, wc = w >> 2;
  const int row0 = blockIdx.x * 64;
  const int colg = (lane & 7) ^ (lane >> 3);       // pre-swizzled global 16B-col for gload16
  if (tid < 64) sqpart[tid] = 0.f;
  f32x4 acc[4] = {{0.f,0.f,0.f,0.f}};
  #pragma unroll 1
  for (int k0 = 0; k0 < DD; k0 += 64){
    // stage A tile (64 rows x 64 k): fp32 -> hi/lo bf16, swizzled reg-staging
    #pragma unroll
    for (int i = 0; i < 2; ++i){
      int u = tid * 2 + i;
      int r = u >> 4, kc = (u & 15) * 4;
      float4 v = *(const float4*)(batch + (size_t)(row0 + r) * DD + k0 + kc);
      short4 hv, lv;
      hv.x = f2bf(v.x); lv.x = f2bf(v.x - bf2f(hv.x));
      hv.y = f2bf(v.y); lv.y = f2bf(v.y - bf2f(hv.y));
      hv.z = f2bf(v.z); lv.z = f2bf(v.z - bf2f(hv.z));
      hv.w = f2bf(v.w); lv.w = f2bf(v.w - bf2f(hv.w));
      int sidx = r * 64 + (((kc >> 3) ^ (r & 7)) << 3) + (kc & 7);
      *(short4*)&Ah[sidx] = hv;
      *(short4*)&Al[sidx] = lv;
    }
    // stage P tile (128 cols x 64 k) via global_load_lds: linear LDS dest + pre-swizzled source
    #pragma unroll
    for (int q = 0; q < 2; ++q){
      int prow = w * 16 + q * 8 + (lane >> 3);
      const short* gh = pt_hi + prow * DD + k0 + colg * 8;
      const short* gl = pt_lo + prow * DD + k0 + colg * 8;
      gload16(gh, &Ph[w * 1024 + q * 512]);
      gload16(gl, &Pl[w * 1024 + q * 512]);
    }
    __syncthreads();
    #pragma unroll
    for (int ks = 0; ks < 2; ++ks){
      int c16 = ks * 4 + lg;
      bf16x8 ah = *(const bf16x8*)&Ah[swz(wr * 16 + lr, c16)];
      bf16x8 al = *(const bf16x8*)&Al[swz(wr * 16 + lr, c16)];
      bf16x8 bh[4], bl[4];
      #pragma unroll
      for (int n = 0; n < 4; ++n){
        int prow = wc * 64 + n * 16 + lr;
        bh[n] = *(const bf16x8*)&Ph[swz(prow, c16)];
        bl[n] = *(const bf16x8*)&Pl[swz(prow, c16)];
      }
      #pragma unroll
      for (int n = 0; n < 4; ++n)
        acc[n] = __builtin_amdgcn_mfma_f32_16x16x32_bf16(ah, bh[n], acc[n], 0, 0, 0);
      #pragma unroll
      for (int n = 0; n < 4; ++n)
        acc[n] = __builtin_amdgcn_mfma_f32_16x16x32_bf16(ah, bl[n], acc[n], 0, 0, 0);
      #pragma unroll
      for (int n = 0; n < 4; ++n)
        acc[n] = __builtin_amdgcn_mfma_f32_16x16x32_bf16(al, bh[n], acc[n], 0, 0, 0);
    }
    __syncthreads();
  }
  // epilogue: split into hi/lo bf16 -> LDS bounce (Ph/Pl are dead) -> coalesced stores
  short* Th = Ph;   // 64 x 128 bf16 = 16 KB
  short* Tl = Pl;
  #pragma unroll
  for (int r = 0; r < 4; ++r){
    int lrow = wr * 16 + lg * 4 + r;
    float s = 0.f;
    #pragma unroll
    for (int n = 0; n < 4; ++n){
      float x = acc[n][r];
      s += x * x;
      int col = wc * 64 + n * 16 + lr;
      short h = f2bf(x);
      short l = f2bf(x - bf2f(h));
      Th[lrow * 128 + col] = h;
      Tl[lrow * 128 + col] = l;
    }
    s += __shfl_xor(s, 1);
    s += __shfl_xor(s, 2);
    s += __shfl_xor(s, 4);
    s += __shfl_xor(s, 8);
    if (lr == 0) atomicAdd(&sqpart[lrow], s);
  }
  __syncthreads();
  #pragma unroll
  for (int ps = 0; ps < 2; ++ps){
    int u = ps * 512 + tid;          // 1024 chunks of 8 shorts (16 B)
    int row = u >> 4, c8 = (u & 15) * 8;
    *(int4*)&t_hi[(size_t)(row0 + row) * RR + c8] = *(int4*)&Th[row * 128 + c8];
    *(int4*)&t_lo[(size_t)(row0 + row) * RR + c8] = *(int4*)&Tl[row * 128 + c8];
  }
  if (tid < 64) sqv[row0 + tid] = sqpart[tid];
}

// -------- Kernel 2: symmetric pairwise distances. Tile-pairs ti<=tj; grid.x = batch -> XCD.
// Direct tile bounced through LDS (panels dead post-loop) for coalesced float4 stores;
// mirror tile written column-major float4 from registers.
__global__ __launch_bounds__(256, 2) void k2_dist(const short* __restrict__ t_hi,
                                                  const short* __restrict__ t_lo,
                                                  const float* __restrict__ sqv,
                                                  float* __restrict__ out){
  __shared__ __align__(16) char smem[65536];   // Ah|Al|Bh|Bl 16 KB each; aliased f32 tile
  short* Ah = (short*)smem;
  short* Al = (short*)(smem + 16384);
  short* Bh = (short*)(smem + 32768);
  short* Bl = (short*)(smem + 49152);
  float* ftile = (float*)smem;                 // 128 x 128 f32 = 64 KB
  const int tid = threadIdx.x;
  const int w = tid >> 6, lane = tid & 63;
  const int lr = lane & 15, lg = lane >> 4;
  const int bi = blockIdx.x;                   // batch -> XCD (2 MB t panel fits 4 MB L2)
  // decode tile pair (ti <= tj) from blockIdx.y in [0,136)
  int p = blockIdx.y;
  int ti = 0;
  while (p >= 16 - ti){ p -= 16 - ti; ++ti; }
  const int tj = ti + p;
  const int i0 = ti * 128, j0 = tj * 128;
  const size_t tbase = (size_t)bi * SS * RR;
  const int colg = (lane & 7) ^ (lane >> 3);

  f32x4 acc[16] = {{0.f,0.f,0.f,0.f}};
  #pragma unroll 1
  for (int k0 = 0; k0 < RR; k0 += 64){
    // stage 4 panels (128 x 64 bf16 each) via global_load_lds, pre-swizzled source
    #pragma unroll
    for (int q = 0; q < 4; ++q){
      int rloc = w * 32 + q * 8 + (lane >> 3);
      size_t goffA = tbase + (size_t)(i0 + rloc) * RR + k0 + colg * 8;
      size_t goffB = tbase + (size_t)(j0 + rloc) * RR + k0 + colg * 8;
      int ldst = w * 2048 + q * 512;
      gload16(t_hi + goffA, &Ah[ldst]);
      gload16(t_lo + goffA, &Al[ldst]);
      gload16(t_hi + goffB, &Bh[ldst]);
      gload16(t_lo + goffB, &Bl[ldst]);
    }
    __syncthreads();
    #pragma unroll
    for (int ks = 0; ks < 2; ++ks){
      int c16 = ks * 4 + lg;
      bf16x8 ah[2], al[2];
      #pragma unroll
      for (int rt = 0; rt < 2; ++rt){
        int arow = w * 32 + rt * 16 + lr;
        ah[rt] = *(const bf16x8*)&Ah[swz(arow, c16)];
        al[rt] = *(const bf16x8*)&Al[swz(arow, c16)];
      }
      bf16x8 bh[8], bl[8];
      #pragma unroll
      for (int n = 0; n < 8; ++n){
        int brow = n * 16 + lr;
        bh[n] = *(const bf16x8*)&Bh[swz(brow, c16)];
        bl[n] = *(const bf16x8*)&Bl[swz(brow, c16)];
      }
      #pragma unroll
      for (int rt = 0; rt < 2; ++rt)
        #pragma unroll
        for (int n = 0; n < 8; ++n)
          acc[rt * 8 + n] = __builtin_amdgcn_mfma_f32_16x16x32_bf16(ah[rt], bh[n], acc[rt * 8 + n], 0, 0, 0);
      #pragma unroll
      for (int rt = 0; rt < 2; ++rt)
        #pragma unroll
        for (int n = 0; n < 8; ++n)
          acc[rt * 8 + n] = __builtin_amdgcn_mfma_f32_16x16x32_bf16(ah[rt], bl[n], acc[rt * 8 + n], 0, 0, 0);
      #pragma unroll
      for (int rt = 0; rt < 2; ++rt)
        #pragma unroll
        for (int n = 0; n < 8; ++n)
          acc[rt * 8 + n] = __builtin_amdgcn_mfma_f32_16x16x32_bf16(al[rt], bh[n], acc[rt * 8 + n], 0, 0, 0);
    }
    __syncthreads();
  }
  float* outb = out + (size_t)bi * SS * SS;
  const float* sqb = sqv + bi * SS;
  // stash dots into LDS (panels dead after final barrier above)
  #pragma unroll
  for (int rt = 0; rt < 2; ++rt)
    #pragma unroll
    for (int n = 0; n < 8; ++n)
      #pragma unroll
      for (int r = 0; r < 4; ++r)
        ftile[(w * 32 + rt * 16 + lg * 4 + r) * 128 + n * 16 + lr] = acc[rt * 8 + n][r];
  __syncthreads();
  // direct tile: row-major float4, fully coalesced (1 KB / instruction / wave)
  #pragma unroll
  for (int v = 0; v < 16; ++v){
    int u = v * 256 + tid;
    int row = u >> 5, c4 = (u & 31) * 4;
    float4 d = *(float4*)&ftile[row * 128 + c4];
    float si = sqb[i0 + row];
    float4 sj = *(const float4*)&sqb[j0 + c4];
    float4 o;
    o.x = si + sj.x - 2.0f * d.x;
    o.y = si + sj.y - 2.0f * d.y;
    o.z = si + sj.z - 2.0f * d.z;
    o.w = si + sj.w - 2.0f * d.w;
    *(float4*)&outb[(size_t)(i0 + row) * SS + j0 + c4] = o;
  }
  // mirror tile: column-major float4 from registers (4 lanes/lg combine to 64 B)
  if (ti != tj){
    #pragma unroll
    for (int rt = 0; rt < 2; ++rt){
      int rbase = w * 32 + rt * 16 + lg * 4;
      float4 si4 = *(const float4*)&sqb[i0 + rbase];
      #pragma unroll
      for (int n = 0; n < 8; ++n){
        int col = n * 16 + lr;
        float sj = sqb[j0 + col];
        float4 mv;
        mv.x = si4.x + sj - 2.0f * acc[rt * 8 + n][0];
        mv.y = si4.y + sj - 2.0f * acc[rt * 8 + n][1];
        mv.z = si4.z + sj - 2.0f * acc[rt * 8 + n][2];
        mv.w = si4.w + sj - 2.0f * acc[rt * 8 + n][3];
        *(float4*)&outb[(size_t)(j0 + col) * SS + i0 + rbase] = mv;
      }
    }
  }
}

extern "C" void kernel_launch(void* const* d_in, const int* in_sizes, int n_in,
                              void* d_out, int out_size, void* d_ws, size_t ws_size,
                              hipStream_t stream) {
  const float* batch = (const float*)d_in[0];   // (8, 2048, 1024) f32
  const float* proj  = (const float*)d_in[1];   // (1024, 128) f32
  float* out = (float*)d_out;                   // (8, 2048, 2048) f32
  char* ws = (char*)d_ws;

  short* pt_hi = (short*)(ws);                          // 128x1024 bf16 = 256 KB
  short* pt_lo = (short*)(ws + 262144);                 // 256 KB
  short* t_hi  = (short*)(ws + 524288);                 // 16384x128 bf16 = 4 MB
  short* t_lo  = (short*)(ws + 4718592);                // 4 MB
  float* sqv   = (float*)(ws + 8912896);                // 16384 f32 = 64 KB

  k0_proj<<<dim3(16, 2), 256, 0, stream>>>(proj, pt_hi, pt_lo);
  k1_gemm1<<<dim3(256), 512, 0, stream>>>(batch, pt_hi, pt_lo, t_hi, t_lo, sqv);
  k2_dist<<<dim3(8, 136), 256, 0, stream>>>(t_hi, t_lo, sqv, out);
}

// Round 5
// 214.539 us; speedup vs baseline: 1.0483x; 1.0034x over previous
//
#include <hip/hip_runtime.h>
#include <hip/hip_bf16.h>

typedef short bf16x8 __attribute__((ext_vector_type(8)));
typedef float f32x4 __attribute__((ext_vector_type(4)));

#define NB 8
#define SS 2048
#define DD 1024
#define RR 128

__device__ __forceinline__ short f2bf(float x){
  unsigned u = __float_as_uint(x);
  u += 0x7fffu + ((u >> 16) & 1u);
  return (short)(u >> 16);
}
__device__ __forceinline__ float bf2f(short h){
  return __uint_as_float(((unsigned)(unsigned short)h) << 16);
}
__device__ __forceinline__ void gload16(const void* g, void* l){
  __builtin_amdgcn_global_load_lds((const __attribute__((address_space(1))) unsigned*)g,
                                   (__attribute__((address_space(3))) unsigned*)l, 16, 0, 0);
}
// swizzled short-index into a [rows][64] bf16 tile (k1 only)
__device__ __forceinline__ int swz(int row, int c16){
  return row * 64 + ((c16 ^ (row & 7)) << 3);
}

// -------- Kernel 0: transpose proj (D x R) -> pt (R x D), split into bf16 hi/lo
__global__ __launch_bounds__(256) void k0_proj(const float* __restrict__ proj,
                                               short* __restrict__ pt_hi,
                                               short* __restrict__ pt_lo){
  __shared__ float tile[64][65];
  const int d0 = blockIdx.x * 64, r0 = blockIdx.y * 64;
  const int tid = threadIdx.x;
  #pragma unroll
  for (int i = 0; i < 16; ++i){
    int u = i * 256 + tid;
    int d = u >> 6, r = u & 63;
    tile[d][r] = proj[(d0 + d) * RR + r0 + r];
  }
  __syncthreads();
  #pragma unroll
  for (int i = 0; i < 16; ++i){
    int u = i * 256 + tid;
    int r = u >> 6, d = u & 63;
    float x = tile[d][r];
    short h = f2bf(x);
    short l = f2bf(x - bf2f(h));
    pt_hi[(r0 + r) * DD + d0 + d] = h;
    pt_lo[(r0 + r) * DD + d0 + d] = l;
  }
}

// -------- Kernel 1: t = batch @ proj via split-bf16 MFMA (hh + hl + lh; ll dropped). UNCHANGED.
__global__ __launch_bounds__(512, 2) void k1_gemm1(const float* __restrict__ batch,
                                                   const short* __restrict__ pt_hi,
                                                   const short* __restrict__ pt_lo,
                                                   short* __restrict__ t_hi,
                                                   short* __restrict__ t_lo,
                                                   float* __restrict__ sqv){
  __shared__ __align__(16) char smem[49408];   // Ah 8K | Al 8K | Ph 16K | Pl 16K | sqpart 256B
  short* Ah = (short*)smem;
  short* Al = (short*)(smem + 8192);
  short* Ph = (short*)(smem + 16384);
  short* Pl = (short*)(smem + 32768);
  float* sqpart = (float*)(smem + 49152);
  const int tid = threadIdx.x;
  const int w = tid >> 6, lane = tid & 63;
  const int lr = lane & 15, lg = lane >> 4;
  const int wr = w & 3, wc = w >> 2;
  const int row0 = blockIdx.x * 64;
  const int colg = (lane & 7) ^ (lane >> 3);
  if (tid < 64) sqpart[tid] = 0.f;
  f32x4 acc[4] = {{0.f,0.f,0.f,0.f}};
  #pragma unroll 1
  for (int k0 = 0; k0 < DD; k0 += 64){
    #pragma unroll
    for (int i = 0; i < 2; ++i){
      int u = tid * 2 + i;
      int r = u >> 4, kc = (u & 15) * 4;
      float4 v = *(const float4*)(batch + (size_t)(row0 + r) * DD + k0 + kc);
      short4 hv, lv;
      hv.x = f2bf(v.x); lv.x = f2bf(v.x - bf2f(hv.x));
      hv.y = f2bf(v.y); lv.y = f2bf(v.y - bf2f(hv.y));
      hv.z = f2bf(v.z); lv.z = f2bf(v.z - bf2f(hv.z));
      hv.w = f2bf(v.w); lv.w = f2bf(v.w - bf2f(hv.w));
      int sidx = r * 64 + (((kc >> 3) ^ (r & 7)) << 3) + (kc & 7);
      *(short4*)&Ah[sidx] = hv;
      *(short4*)&Al[sidx] = lv;
    }
    #pragma unroll
    for (int q = 0; q < 2; ++q){
      int prow = w * 16 + q * 8 + (lane >> 3);
      const short* gh = pt_hi + prow * DD + k0 + colg * 8;
      const short* gl = pt_lo + prow * DD + k0 + colg * 8;
      gload16(gh, &Ph[w * 1024 + q * 512]);
      gload16(gl, &Pl[w * 1024 + q * 512]);
    }
    __syncthreads();
    #pragma unroll
    for (int ks = 0; ks < 2; ++ks){
      int c16 = ks * 4 + lg;
      bf16x8 ah = *(const bf16x8*)&Ah[swz(wr * 16 + lr, c16)];
      bf16x8 al = *(const bf16x8*)&Al[swz(wr * 16 + lr, c16)];
      bf16x8 bh[4], bl[4];
      #pragma unroll
      for (int n = 0; n < 4; ++n){
        int prow = wc * 64 + n * 16 + lr;
        bh[n] = *(const bf16x8*)&Ph[swz(prow, c16)];
        bl[n] = *(const bf16x8*)&Pl[swz(prow, c16)];
      }
      #pragma unroll
      for (int n = 0; n < 4; ++n)
        acc[n] = __builtin_amdgcn_mfma_f32_16x16x32_bf16(ah, bh[n], acc[n], 0, 0, 0);
      #pragma unroll
      for (int n = 0; n < 4; ++n)
        acc[n] = __builtin_amdgcn_mfma_f32_16x16x32_bf16(ah, bl[n], acc[n], 0, 0, 0);
      #pragma unroll
      for (int n = 0; n < 4; ++n)
        acc[n] = __builtin_amdgcn_mfma_f32_16x16x32_bf16(al, bh[n], acc[n], 0, 0, 0);
    }
    __syncthreads();
  }
  short* Th = Ph;
  short* Tl = Pl;
  #pragma unroll
  for (int r = 0; r < 4; ++r){
    int lrow = wr * 16 + lg * 4 + r;
    float s = 0.f;
    #pragma unroll
    for (int n = 0; n < 4; ++n){
      float x = acc[n][r];
      s += x * x;
      int col = wc * 64 + n * 16 + lr;
      short h = f2bf(x);
      short l = f2bf(x - bf2f(h));
      Th[lrow * 128 + col] = h;
      Tl[lrow * 128 + col] = l;
    }
    s += __shfl_xor(s, 1);
    s += __shfl_xor(s, 2);
    s += __shfl_xor(s, 4);
    s += __shfl_xor(s, 8);
    if (lr == 0) atomicAdd(&sqpart[lrow], s);
  }
  __syncthreads();
  #pragma unroll
  for (int ps = 0; ps < 2; ++ps){
    int u = ps * 512 + tid;
    int row = u >> 4, c8 = (u & 15) * 8;
    *(int4*)&t_hi[(size_t)(row0 + row) * RR + c8] = *(int4*)&Th[row * 128 + c8];
    *(int4*)&t_lo[(size_t)(row0 + row) * RR + c8] = *(int4*)&Tl[row * 128 + c8];
  }
  if (tid < 64) sqv[row0 + tid] = sqpart[tid];
}

// -------- Kernel 2 (REWRITE): persistent blocks, full-K LDS panels, multi-tile loop.
// 256 blocks x 512 thr, 1 block/CU, 128 KB LDS. bi = blockIdx&7 -> XCD-pinned batch.
// Block handles tile-pairs p = (blockIdx>>3) + 32*s, s=0.. (4 or 5 tiles).
__global__ __launch_bounds__(512, 1) void k2_dist(const short* __restrict__ t_hi,
                                                  const short* __restrict__ t_lo,
                                                  const float* __restrict__ sqv,
                                                  float* __restrict__ out){
  __shared__ short lds[65536];   // 128 KB: Ah | Al | Bh | Bl, 16384 shorts ([128][128]) each
  const int tid = threadIdx.x;
  const int w = tid >> 6, lane = tid & 63;
  const int lr = lane & 15, lg = lane >> 4;
  const int srow = ((w & 1) << 2) | (lane >> 4);   // stage-row & 7
  const int colg = (lane & 15) ^ srow;             // pre-swizzled global 16B slot
  const int bi = blockIdx.x & 7;                   // batch == XCD (1 MB t panel in local L2)
  const int lidx = blockIdx.x >> 3;                // [0,32) tile-pair stride start
  const size_t tbase = (size_t)bi * SS * RR;
  float* outb = out + (size_t)bi * SS * SS;
  const float* sqb = sqv + bi * SS;

  auto decodeP = [&](int p, int& i0, int& j0, bool& dg){
    int ti = 0;
    while (p >= 16 - ti){ p -= 16 - ti; ++ti; }
    int tj = ti + p;
    i0 = ti * 128; j0 = tj * 128; dg = (ti == tj);
  };
  auto stageTile = [&](int i0, int j0, bool dg){
    #pragma unroll
    for (int q = 0; q < 4; ++q){
      int rl = q * 32 + w * 4;                     // wave-uniform LDS row base (4 rows/wave-instr)
      int gr = rl + (lane >> 4);                   // this lane's source row
      size_t oA = tbase + (size_t)(i0 + gr) * RR + colg * 8;
      gload16(t_hi + oA, &lds[rl * 128]);
      gload16(t_lo + oA, &lds[16384 + rl * 128]);
      if (!dg){
        size_t oB = tbase + (size_t)(j0 + gr) * RR + colg * 8;
        gload16(t_hi + oB, &lds[32768 + rl * 128]);
        gload16(t_lo + oB, &lds[49152 + rl * 128]);
      }
    }
  };

  int p = lidx;
  int i0, j0; bool dg;
  decodeP(p, i0, j0, dg);
  stageTile(i0, j0, dg);
  while (true){
    __syncthreads();                               // stage visible (also drains older stores)
    const int bh0 = dg ? 0 : 32768, bl0 = dg ? 16384 : 49152;
    f32x4 acc[8] = {{0.f,0.f,0.f,0.f}};
    const int ar = w * 16 + lr;
    const int aoff = ar * 128;
    const int asw = (ar & 7);
    #pragma unroll
    for (int ks = 0; ks < 4; ++ks){
      int c16 = ks * 4 + lg;
      bf16x8 ah = *(const bf16x8*)&lds[aoff + ((c16 ^ asw) << 3)];
      bf16x8 al = *(const bf16x8*)&lds[16384 + aoff + ((c16 ^ asw) << 3)];
      bf16x8 bh[8], bl[8];
      #pragma unroll
      for (int n = 0; n < 8; ++n){
        int br = n * 16 + lr;
        int off = br * 128 + ((c16 ^ (br & 7)) << 3);
        bh[n] = *(const bf16x8*)&lds[bh0 + off];
        bl[n] = *(const bf16x8*)&lds[bl0 + off];
      }
      #pragma unroll
      for (int n = 0; n < 8; ++n)
        acc[n] = __builtin_amdgcn_mfma_f32_16x16x32_bf16(ah, bh[n], acc[n], 0, 0, 0);
      #pragma unroll
      for (int n = 0; n < 8; ++n)
        acc[n] = __builtin_amdgcn_mfma_f32_16x16x32_bf16(ah, bl[n], acc[n], 0, 0, 0);
      #pragma unroll
      for (int n = 0; n < 8; ++n)
        acc[n] = __builtin_amdgcn_mfma_f32_16x16x32_bf16(al, bh[n], acc[n], 0, 0, 0);
    }
    __syncthreads();                               // all frag reads done before overwrite
    int np = p + 32;
    bool more = (np < 136);
    int ni0, nj0; bool ndg;
    if (more){ decodeP(np, ni0, nj0, ndg); stageTile(ni0, nj0, ndg); }  // loads issued first
    // epilogue: stores issued after next-tile loads -> overlap until next barrier drain
    {
      int rbase = w * 16 + lg * 4;
      float4 si4 = *(const float4*)&sqb[i0 + rbase];
      #pragma unroll
      for (int n = 0; n < 8; ++n){
        int col = n * 16 + lr;
        float sj = sqb[j0 + col];
        float4 v;
        v.x = si4.x + sj - 2.0f * acc[n][0];
        v.y = si4.y + sj - 2.0f * acc[n][1];
        v.z = si4.z + sj - 2.0f * acc[n][2];
        v.w = si4.w + sj - 2.0f * acc[n][3];
        size_t ro = (size_t)(i0 + rbase) * SS + (j0 + col);
        outb[ro] = v.x;
        outb[ro + SS] = v.y;
        outb[ro + 2 * SS] = v.z;
        outb[ro + 3 * SS] = v.w;
        if (!dg) *(float4*)&outb[(size_t)(j0 + col) * SS + (i0 + rbase)] = v;
      }
    }
    if (!more) break;
    p = np; i0 = ni0; j0 = nj0; dg = ndg;
  }
}

extern "C" void kernel_launch(void* const* d_in, const int* in_sizes, int n_in,
                              void* d_out, int out_size, void* d_ws, size_t ws_size,
                              hipStream_t stream) {
  const float* batch = (const float*)d_in[0];   // (8, 2048, 1024) f32
  const float* proj  = (const float*)d_in[1];   // (1024, 128) f32
  float* out = (float*)d_out;                   // (8, 2048, 2048) f32
  char* ws = (char*)d_ws;

  short* pt_hi = (short*)(ws);                          // 128x1024 bf16 = 256 KB
  short* pt_lo = (short*)(ws + 262144);                 // 256 KB
  short* t_hi  = (short*)(ws + 524288);                 // 16384x128 bf16 = 4 MB
  short* t_lo  = (short*)(ws + 4718592);                // 4 MB
  float* sqv   = (float*)(ws + 8912896);                // 16384 f32 = 64 KB

  k0_proj<<<dim3(16, 2), 256, 0, stream>>>(proj, pt_hi, pt_lo);
  k1_gemm1<<<dim3(256), 512, 0, stream>>>(batch, pt_hi, pt_lo, t_hi, t_lo, sqv);
  k2_dist<<<dim3(256), 512, 0, stream>>>(t_hi, t_lo, sqv, out);
}

// Round 8
// 207.900 us; speedup vs baseline: 1.0818x; 1.0319x over previous
//
#include <hip/hip_runtime.h>
#include <hip/hip_bf16.h>

typedef short bf16x8 __attribute__((ext_vector_type(8)));
typedef float f32x4 __attribute__((ext_vector_type(4)));

#define NB 8
#define SS 2048
#define DD 1024
#define RR 128

__device__ __forceinline__ short f2bf(float x){
  unsigned u = __float_as_uint(x);
  u += 0x7fffu + ((u >> 16) & 1u);
  return (short)(u >> 16);
}
__device__ __forceinline__ float bf2f(short h){
  return __uint_as_float(((unsigned)(unsigned short)h) << 16);
}
__device__ __forceinline__ void gload16(const void* g, void* l){
  __builtin_amdgcn_global_load_lds((const __attribute__((address_space(1))) unsigned*)g,
                                   (__attribute__((address_space(3))) unsigned*)l, 16, 0, 0);
}
// swizzled short-index into a [rows][64] bf16 tile (k1)
__device__ __forceinline__ int swz(int row, int c16){
  return row * 64 + ((c16 ^ (row & 7)) << 3);
}

// -------- Kernel 0: transpose proj (D x R) -> pt (R x D), split into bf16 hi/lo
__global__ __launch_bounds__(256) void k0_proj(const float* __restrict__ proj,
                                               short* __restrict__ pt_hi,
                                               short* __restrict__ pt_lo){
  __shared__ float tile[64][65];
  const int d0 = blockIdx.x * 64, r0 = blockIdx.y * 64;
  const int tid = threadIdx.x;
  #pragma unroll
  for (int i = 0; i < 16; ++i){
    int u = i * 256 + tid;
    int d = u >> 6, r = u & 63;
    tile[d][r] = proj[(d0 + d) * RR + r0 + r];
  }
  __syncthreads();
  #pragma unroll
  for (int i = 0; i < 16; ++i){
    int u = i * 256 + tid;
    int r = u >> 6, d = u & 63;
    float x = tile[d][r];
    short h = f2bf(x);
    short l = f2bf(x - bf2f(h));
    pt_hi[(r0 + r) * DD + d0 + d] = h;
    pt_lo[(r0 + r) * DD + d0 + d] = l;
  }
}

// -------- Kernel 1: t = batch @ proj via split-bf16 MFMA (hh + hl + lh; ll dropped).
// Stores t_hi (bf16) only + fp32 row norms. Proven structure from round 5.
__global__ __launch_bounds__(512, 2) void k1_gemm1(const float* __restrict__ batch,
                                                   const short* __restrict__ pt_hi,
                                                   const short* __restrict__ pt_lo,
                                                   short* __restrict__ t_hi,
                                                   float* __restrict__ sqv){
  __shared__ __align__(16) char smem[49408];   // Ah 8K | Al 8K | Ph 16K | Pl 16K | sqpart 256B
  short* Ah = (short*)smem;
  short* Al = (short*)(smem + 8192);
  short* Ph = (short*)(smem + 16384);
  short* Pl = (short*)(smem + 32768);
  float* sqpart = (float*)(smem + 49152);
  const int tid = threadIdx.x;
  const int w = tid >> 6, lane = tid & 63;
  const int lr = lane & 15, lg = lane >> 4;
  const int wr = w & 3, wc = w >> 2;
  const int row0 = blockIdx.x * 64;
  const int colg = (lane & 7) ^ (lane >> 3);
  if (tid < 64) sqpart[tid] = 0.f;
  f32x4 acc[4] = {{0.f,0.f,0.f,0.f}};
  #pragma unroll 1
  for (int k0 = 0; k0 < DD; k0 += 64){
    #pragma unroll
    for (int i = 0; i < 2; ++i){
      int u = tid * 2 + i;
      int r = u >> 4, kc = (u & 15) * 4;
      float4 v = *(const float4*)(batch + (size_t)(row0 + r) * DD + k0 + kc);
      short4 hv, lv;
      hv.x = f2bf(v.x); lv.x = f2bf(v.x - bf2f(hv.x));
      hv.y = f2bf(v.y); lv.y = f2bf(v.y - bf2f(hv.y));
      hv.z = f2bf(v.z); lv.z = f2bf(v.z - bf2f(hv.z));
      hv.w = f2bf(v.w); lv.w = f2bf(v.w - bf2f(hv.w));
      int sidx = r * 64 + (((kc >> 3) ^ (r & 7)) << 3) + (kc & 7);
      *(short4*)&Ah[sidx] = hv;
      *(short4*)&Al[sidx] = lv;
    }
    #pragma unroll
    for (int q = 0; q < 2; ++q){
      int prow = w * 16 + q * 8 + (lane >> 3);
      gload16(pt_hi + prow * DD + k0 + colg * 8, &Ph[w * 1024 + q * 512]);
      gload16(pt_lo + prow * DD + k0 + colg * 8, &Pl[w * 1024 + q * 512]);
    }
    __syncthreads();
    #pragma unroll
    for (int ks = 0; ks < 2; ++ks){
      int c16 = ks * 4 + lg;
      bf16x8 ah = *(const bf16x8*)&Ah[swz(wr * 16 + lr, c16)];
      bf16x8 al = *(const bf16x8*)&Al[swz(wr * 16 + lr, c16)];
      bf16x8 bh[4], bl[4];
      #pragma unroll
      for (int n = 0; n < 4; ++n){
        int prow = wc * 64 + n * 16 + lr;
        bh[n] = *(const bf16x8*)&Ph[swz(prow, c16)];
        bl[n] = *(const bf16x8*)&Pl[swz(prow, c16)];
      }
      #pragma unroll
      for (int n = 0; n < 4; ++n)
        acc[n] = __builtin_amdgcn_mfma_f32_16x16x32_bf16(ah, bh[n], acc[n], 0, 0, 0);
      #pragma unroll
      for (int n = 0; n < 4; ++n)
        acc[n] = __builtin_amdgcn_mfma_f32_16x16x32_bf16(ah, bl[n], acc[n], 0, 0, 0);
      #pragma unroll
      for (int n = 0; n < 4; ++n)
        acc[n] = __builtin_amdgcn_mfma_f32_16x16x32_bf16(al, bh[n], acc[n], 0, 0, 0);
    }
    __syncthreads();
  }
  // epilogue: round t to bf16 -> LDS bounce (Ph dead) -> coalesced stores + norms
  short* Th = Ph;
  #pragma unroll
  for (int r = 0; r < 4; ++r){
    int lrow = wr * 16 + lg * 4 + r;
    float s = 0.f;
    #pragma unroll
    for (int n = 0; n < 4; ++n){
      float x = acc[n][r];
      s += x * x;
      int col = wc * 64 + n * 16 + lr;
      Th[lrow * 128 + col] = f2bf(x);
    }
    s += __shfl_xor(s, 1);
    s += __shfl_xor(s, 2);
    s += __shfl_xor(s, 4);
    s += __shfl_xor(s, 8);
    if (lr == 0) atomicAdd(&sqpart[lrow], s);
  }
  __syncthreads();
  #pragma unroll
  for (int ps = 0; ps < 2; ++ps){
    int u = ps * 512 + tid;
    int row = u >> 4, c8 = (u & 15) * 8;
    *(int4*)&t_hi[(size_t)(row0 + row) * RR + c8] = *(int4*)&Th[row * 128 + c8];
  }
  if (tid < 64) sqv[row0 + tid] = sqpart[tid];
}

// -------- Kernel 2: symmetric pairwise distances, hi-only MFMA (error ~0.1 << 2.0 tol).
// grid (8, 136): x = batch -> XCD pin; y = tile-pair ti<=tj. 64 KB LDS, 2 blocks/CU.
__global__ __launch_bounds__(512, 4) void k2_dist(const short* __restrict__ t_hi,
                                                  const float* __restrict__ sqv,
                                                  float* __restrict__ out){
  __shared__ __align__(16) short lds[32768];   // 64 KB: A | B panels, [128][128] bf16 swizzled
  float* ftile = (float*)lds;                  // aliased 128x128 f32 for store bounce
  const int tid = threadIdx.x;
  const int w = tid >> 6, lane = tid & 63;
  const int lr = lane & 15, lg = lane >> 4;
  const int bi = blockIdx.x;                   // batch == XCD (0.5 MB hi panel in local L2)
  int p = blockIdx.y;
  int ti = 0;
  while (p >= 16 - ti){ p -= 16 - ti; ++ti; }
  const int tj = ti + p;
  const int i0 = ti * 128, j0 = tj * 128;
  const bool dg = (ti == tj);
  const size_t tbase = (size_t)bi * SS * RR;
  float* outb = out + (size_t)bi * SS * SS;
  const float* sqb = sqv + bi * SS;
  const int srow = ((w & 1) << 2) | (lane >> 4);   // staged-row & 7
  const int colg = (lane & 15) ^ srow;             // pre-swizzled global 16B slot

  // stage A (and B if off-diagonal): 4 rounds x 32 rows, linear LDS + pre-swizzled source
  #pragma unroll
  for (int q = 0; q < 4; ++q){
    int rl = q * 32 + w * 4;
    int gr = rl + (lane >> 4);
    gload16(t_hi + tbase + (size_t)(i0 + gr) * RR + colg * 8, &lds[rl * 128]);
    if (!dg)
      gload16(t_hi + tbase + (size_t)(j0 + gr) * RR + colg * 8, &lds[16384 + rl * 128]);
  }
  __syncthreads();

  const int bh0 = dg ? 0 : 16384;
  f32x4 acc[8] = {{0.f,0.f,0.f,0.f}};
  const int ar = w * 16 + lr;
  const int aoff = ar * 128;
  const int asw = ar & 7;
  #pragma unroll
  for (int ks = 0; ks < 4; ++ks){
    int c16 = ks * 4 + lg;
    bf16x8 ah = *(const bf16x8*)&lds[aoff + ((c16 ^ asw) << 3)];
    bf16x8 bh[8];
    #pragma unroll
    for (int n = 0; n < 8; ++n){
      int br = n * 16 + lr;
      bh[n] = *(const bf16x8*)&lds[bh0 + br * 128 + ((c16 ^ (br & 7)) << 3)];
    }
    #pragma unroll
    for (int n = 0; n < 8; ++n)
      acc[n] = __builtin_amdgcn_mfma_f32_16x16x32_bf16(ah, bh[n], acc[n], 0, 0, 0);
  }
  __syncthreads();                             // all frag reads done; panels dead

  // mirror tile first, straight from registers (column-major float4)
  if (!dg){
    int rbase = w * 16 + lg * 4;
    float4 si4 = *(const float4*)&sqb[i0 + rbase];
    #pragma unroll
    for (int n = 0; n < 8; ++n){
      int col = n * 16 + lr;
      float sj = sqb[j0 + col];
      float4 mv;
      mv.x = si4.x + sj - 2.0f * acc[n][0];
      mv.y = si4.y + sj - 2.0f * acc[n][1];
      mv.z = si4.z + sj - 2.0f * acc[n][2];
      mv.w = si4.w + sj - 2.0f * acc[n][3];
      *(float4*)&outb[(size_t)(j0 + col) * SS + (i0 + rbase)] = mv;
    }
  }
  // direct tile: bounce dots through LDS, then row-major float4 (fully coalesced)
  #pragma unroll
  for (int n = 0; n < 8; ++n)
    #pragma unroll
    for (int r = 0; r < 4; ++r)
      ftile[(w * 16 + lg * 4 + r) * 128 + n * 16 + lr] = acc[n][r];
  __syncthreads();
  #pragma unroll
  for (int v = 0; v < 8; ++v){
    int u = v * 512 + tid;
    int row = u >> 5, c4 = (u & 31) * 4;
    float4 d = *(float4*)&ftile[row * 128 + c4];
    float si = sqb[i0 + row];
    float4 sj = *(const float4*)&sqb[j0 + c4];
    float4 o;
    o.x = si + sj.x - 2.0f * d.x;
    o.y = si + sj.y - 2.0f * d.y;
    o.z = si + sj.z - 2.0f * d.z;
    o.w = si + sj.w - 2.0f * d.w;
    *(float4*)&outb[(size_t)(i0 + row) * SS + j0 + c4] = o;
  }
}

extern "C" void kernel_launch(void* const* d_in, const int* in_sizes, int n_in,
                              void* d_out, int out_size, void* d_ws, size_t ws_size,
                              hipStream_t stream) {
  const float* batch = (const float*)d_in[0];   // (8, 2048, 1024) f32
  const float* proj  = (const float*)d_in[1];   // (1024, 128) f32
  float* out = (float*)d_out;                   // (8, 2048, 2048) f32
  char* ws = (char*)d_ws;

  short* pt_hi = (short*)(ws);                          // 128x1024 bf16 = 256 KB
  short* pt_lo = (short*)(ws + 262144);                 // 256 KB
  short* t_hi  = (short*)(ws + 524288);                 // 16384x128 bf16 = 4 MB
  float* sqv   = (float*)(ws + 4718592);                // 16384 f32 = 64 KB

  k0_proj<<<dim3(16, 2), 256, 0, stream>>>(proj, pt_hi, pt_lo);
  k1_gemm1<<<dim3(256), 512, 0, stream>>>(batch, pt_hi, pt_lo, t_hi, sqv);
  k2_dist<<<dim3(8, 136), 512, 0, stream>>>(t_hi, sqv, out);
}